// Round 2
// baseline (492.076 us; speedup 1.0000x reference)
//
#include <hip/hip_runtime.h>

#define NN 100000
#define EE 1600000
#define FEAT 32
#define HID 64
#define MSG 32
#define GOALD 16
#define OUTD 8
#define UPD_IN 112
#define EPS 1e-5f

// ---------- K1: column stats of x1 = relu(nodes@W_in + b_in) (x1 not stored) ----------
__global__ __launch_bounds__(256) void k_in_stats(
    const float* __restrict__ nodes, const float* __restrict__ W_in,
    const float* __restrict__ b_in, float* __restrict__ stats1)
{
    __shared__ float red[256];
    const int tid = threadIdx.x;
    const int j = tid & 63, slot = tid >> 6;
    float w[FEAT];
#pragma unroll
    for (int k = 0; k < FEAT; ++k) w[k] = W_in[k * HID + j];
    const float bj = b_in[j];
    float lsum = 0.f, lsq = 0.f;
    for (int i = blockIdx.x * 4 + slot; i < NN; i += gridDim.x * 4) {
        const float4* row = (const float4*)(nodes + (size_t)i * FEAT);
        float acc = bj;
#pragma unroll
        for (int q = 0; q < FEAT / 4; ++q) {
            float4 r = row[q];
            acc = fmaf(r.x, w[q * 4 + 0], acc);
            acc = fmaf(r.y, w[q * 4 + 1], acc);
            acc = fmaf(r.z, w[q * 4 + 2], acc);
            acc = fmaf(r.w, w[q * 4 + 3], acc);
        }
        float v = fmaxf(acc, 0.f);
        lsum += v; lsq += v * v;
    }
    red[tid] = lsum; __syncthreads();
    if (tid < 64) atomicAdd(&stats1[tid], red[tid] + red[tid + 64] + red[tid + 128] + red[tid + 192]);
    __syncthreads();
    red[tid] = lsq; __syncthreads();
    if (tid < 64) atomicAdd(&stats1[64 + tid], red[tid] + red[tid + 64] + red[tid + 128] + red[tid + 192]);
}

// ---------- finalize: scale = g*rsqrt(var+eps), shift = beta - mean*scale ----------
__global__ void k_finalize(const float* __restrict__ stats,
                           const float* __restrict__ gamma,
                           const float* __restrict__ beta,
                           float* __restrict__ scsh, int C)
{
    int j = threadIdx.x;
    if (j < C) {
        float mean = stats[j] * (1.f / NN);
        float var  = stats[C + j] * (1.f / NN) - mean * mean;
        float sc = gamma[j] * rsqrtf(var + EPS);
        scsh[j] = sc;
        scsh[C + j] = beta[j] - mean * sc;
    }
}

// ---------- K3: h = BN1(relu(nodes@W_in+b)) stored; x2 = relu(h@W_msg+b) stored; stats2 ----------
__global__ __launch_bounds__(256) void k_h_msg(
    const float* __restrict__ nodes, const float* __restrict__ W_in,
    const float* __restrict__ b_in, const float* __restrict__ sc1,
    const float* __restrict__ W_msg, const float* __restrict__ b_msg,
    float* __restrict__ h_out, float* __restrict__ x2_out,
    float* __restrict__ stats2)
{
    __shared__ float shh[4][HID];
    __shared__ float red[256];
    const int tid = threadIdx.x;
    const int j = tid & 63, slot = tid >> 6;
    const int j2 = j & 31, half = j >> 5;
    float w[FEAT];
#pragma unroll
    for (int k = 0; k < FEAT; ++k) w[k] = W_in[k * HID + j];
    float wm[32];
#pragma unroll
    for (int k = 0; k < 32; ++k) wm[k] = W_msg[(half * 32 + k) * MSG + j2];
    const float bj = b_in[j];
    const float s1 = sc1[j], t1 = sc1[HID + j];
    const float bm = b_msg[j2];
    float lsum = 0.f, lsq = 0.f;
    for (int base = blockIdx.x * 4; base < NN; base += gridDim.x * 4) {
        const int i = base + slot;
        const bool act = i < NN;
        float hv = 0.f;
        if (act) {
            const float4* row = (const float4*)(nodes + (size_t)i * FEAT);
            float acc = bj;
#pragma unroll
            for (int q = 0; q < FEAT / 4; ++q) {
                float4 r = row[q];
                acc = fmaf(r.x, w[q * 4 + 0], acc);
                acc = fmaf(r.y, w[q * 4 + 1], acc);
                acc = fmaf(r.z, w[q * 4 + 2], acc);
                acc = fmaf(r.w, w[q * 4 + 3], acc);
            }
            hv = fmaf(fmaxf(acc, 0.f), s1, t1);
            h_out[(size_t)i * HID + j] = hv;
        }
        shh[slot][j] = hv;
        __syncthreads();
        if (act) {
            const float4* hr = (const float4*)(&shh[slot][half * 32]);
            float acc2 = 0.f;
#pragma unroll
            for (int q = 0; q < 8; ++q) {
                float4 r = hr[q];
                acc2 = fmaf(r.x, wm[q * 4 + 0], acc2);
                acc2 = fmaf(r.y, wm[q * 4 + 1], acc2);
                acc2 = fmaf(r.z, wm[q * 4 + 2], acc2);
                acc2 = fmaf(r.w, wm[q * 4 + 3], acc2);
            }
            acc2 += __shfl_xor(acc2, 32);
            if (half == 0) {
                float v = fmaxf(acc2 + bm, 0.f);
                x2_out[(size_t)i * MSG + j2] = v;
                lsum += v; lsq += v * v;
            }
        }
        __syncthreads();
    }
    red[tid] = (half == 0) ? lsum : 0.f; __syncthreads();
    if (tid < 32) atomicAdd(&stats2[tid], red[tid] + red[tid + 64] + red[tid + 128] + red[tid + 192]);
    __syncthreads();
    red[tid] = (half == 0) ? lsq : 0.f; __syncthreads();
    if (tid < 32) atomicAdd(&stats2[32 + tid], red[tid] + red[tid + 64] + red[tid + 128] + red[tid + 192]);
}

// ---------- K5: edge scatter: agg[dst] += BN2(x2[src])  (affine folded in) ----------
__global__ __launch_bounds__(256) void k_edges(
    const int* __restrict__ esrc, const int* __restrict__ edst,
    const float* __restrict__ x2, const float* __restrict__ sc2,
    float* __restrict__ agg)
{
    const int c = threadIdx.x & 31;
    const float s = sc2[c], t = sc2[MSG + c];
    const int total = EE * 32;
    const int stride = gridDim.x * blockDim.x;
    for (int idx = blockIdx.x * blockDim.x + threadIdx.x; idx < total; idx += stride) {
        const int e = idx >> 5;
        const int si = esrc[e], di = edst[e];
        const float v = x2[(size_t)si * MSG + c];
        atomicAdd(&agg[(size_t)di * MSG + c], fmaf(v, s, t));
    }
}

// ---------- K7: x3 = relu([agg,h,goal]@W_upd + b) -> stored in d_out u-region; stats3 ----------
__global__ __launch_bounds__(256) void k_upd(
    const float* __restrict__ agg, const float* __restrict__ h,
    const float* __restrict__ goal, const float* __restrict__ W_upd,
    const float* __restrict__ b_upd, float* __restrict__ x3_out,
    float* __restrict__ stats3)
{
    __shared__ float cat[4][UPD_IN];
    __shared__ float red[256];
    const int tid = threadIdx.x;
    const int j = tid & 63, slot = tid >> 6;
    float w[UPD_IN];
#pragma unroll
    for (int k = 0; k < UPD_IN; ++k) w[k] = W_upd[k * HID + j];
    const float bj = b_upd[j];
    float lsum = 0.f, lsq = 0.f;
    for (int base = blockIdx.x * 4; base < NN; base += gridDim.x * 4) {
        const int i = base + slot;
        const bool act = i < NN;
        if (act) {
            if (j < 32) cat[slot][j] = agg[(size_t)i * MSG + j];
            cat[slot][32 + j] = h[(size_t)i * HID + j];
            if (j < 16) cat[slot][96 + j] = goal[(size_t)i * GOALD + j];
        }
        __syncthreads();
        if (act) {
            const float4* cr = (const float4*)cat[slot];
            float acc = bj;
#pragma unroll
            for (int q = 0; q < UPD_IN / 4; ++q) {
                float4 r = cr[q];
                acc = fmaf(r.x, w[q * 4 + 0], acc);
                acc = fmaf(r.y, w[q * 4 + 1], acc);
                acc = fmaf(r.z, w[q * 4 + 2], acc);
                acc = fmaf(r.w, w[q * 4 + 3], acc);
            }
            float v = fmaxf(acc, 0.f);
            x3_out[(size_t)i * HID + j] = v;
            lsum += v; lsq += v * v;
        }
        __syncthreads();
    }
    red[tid] = lsum; __syncthreads();
    if (tid < 64) atomicAdd(&stats3[tid], red[tid] + red[tid + 64] + red[tid + 128] + red[tid + 192]);
    __syncthreads();
    red[tid] = lsq; __syncthreads();
    if (tid < 64) atomicAdd(&stats3[64 + tid], red[tid] + red[tid + 64] + red[tid + 128] + red[tid + 192]);
}

// ---------- K9: u = BN3(x3) in-place in d_out; out = u@W_out + b_out -> d_out ----------
__global__ __launch_bounds__(256) void k_out(
    float* __restrict__ x3u, const float* __restrict__ sc3,
    const float* __restrict__ W_out, const float* __restrict__ b_out,
    float* __restrict__ o_out)
{
    __shared__ float shu[4][HID];
    const int tid = threadIdx.x;
    const int j = tid & 63, slot = tid >> 6;
    const int o = j & 7, part = j >> 3;
    const float s3 = sc3[j], t3 = sc3[HID + j];
    float w[8];
#pragma unroll
    for (int k = 0; k < 8; ++k) w[k] = W_out[(part * 8 + k) * OUTD + o];
    const float bo = b_out[o];
    for (int base = blockIdx.x * 4; base < NN; base += gridDim.x * 4) {
        const int i = base + slot;
        const bool act = i < NN;
        float u = 0.f;
        if (act) {
            u = fmaf(x3u[(size_t)i * HID + j], s3, t3);
            x3u[(size_t)i * HID + j] = u;
        }
        shu[slot][j] = u;
        __syncthreads();
        if (act) {
            const float* ur = &shu[slot][part * 8];
            float acc = 0.f;
#pragma unroll
            for (int k = 0; k < 8; ++k) acc = fmaf(ur[k], w[k], acc);
            acc += __shfl_xor(acc, 8);
            acc += __shfl_xor(acc, 16);
            acc += __shfl_xor(acc, 32);
            if (part == 0) o_out[(size_t)i * OUTD + o] = acc + bo;
        }
        __syncthreads();
    }
}

extern "C" void kernel_launch(void* const* d_in, const int* in_sizes, int n_in,
                              void* d_out, int out_size, void* d_ws, size_t ws_size,
                              hipStream_t stream)
{
    (void)in_sizes; (void)n_in; (void)out_size;
    const float* nodes  = (const float*)d_in[0];
    const float* goal   = (const float*)d_in[1];
    const int*   esrc   = (const int*)d_in[2];
    const int*   edst   = (const int*)d_in[3];
    const float* W_in   = (const float*)d_in[6];
    const float* b_in   = (const float*)d_in[7];
    const float* g_in   = (const float*)d_in[8];
    const float* be_in  = (const float*)d_in[9];
    const float* W_msg  = (const float*)d_in[10];
    const float* b_msg  = (const float*)d_in[11];
    const float* g_msg  = (const float*)d_in[12];
    const float* be_msg = (const float*)d_in[13];
    const float* W_upd  = (const float*)d_in[14];
    const float* b_upd  = (const float*)d_in[15];
    const float* g_upd  = (const float*)d_in[16];
    const float* be_upd = (const float*)d_in[17];
    const float* W_out  = (const float*)d_in[18];
    const float* b_out  = (const float*)d_in[19];

    // Workspace layout (stats first, then big buffers): total N*128 + 640 floats
    const size_t need = ((size_t)NN * 128 + 640) * sizeof(float);
    if (ws_size < need) return;  // fail soft (absmax error) instead of OOB-faulting the GPU

    float* st = (float*)d_ws;
    float* stats1 = st;        // 128
    float* stats2 = st + 128;  // 64
    float* stats3 = st + 192;  // 128
    float* sc1    = st + 320;  // 128 (scale64, shift64)
    float* sc2    = st + 448;  // 64  (scale32, shift32)
    float* sc3    = st + 512;  // 128
    float* h   = st + 640;                     // N*64
    float* x2  = h + (size_t)NN * 64;          // N*32
    float* agg = x2 + (size_t)NN * 32;         // N*32

    float* u_out = (float*)d_out;                    // N*64 (x3 then u in-place)
    float* o_out = (float*)d_out + (size_t)NN * HID; // N*8

    hipMemsetAsync(st, 0, 320 * sizeof(float), stream);
    hipMemsetAsync(agg, 0, (size_t)NN * MSG * sizeof(float), stream);

    k_in_stats<<<1024, 256, 0, stream>>>(nodes, W_in, b_in, stats1);
    k_finalize<<<1, 64, 0, stream>>>(stats1, g_in, be_in, sc1, HID);
    k_h_msg<<<1024, 256, 0, stream>>>(nodes, W_in, b_in, sc1, W_msg, b_msg, h, x2, stats2);
    k_finalize<<<1, 64, 0, stream>>>(stats2, g_msg, be_msg, sc2, MSG);
    k_edges<<<4096, 256, 0, stream>>>(esrc, edst, x2, sc2, agg);
    k_upd<<<1024, 256, 0, stream>>>(agg, h, goal, W_upd, b_upd, u_out, stats3);
    k_finalize<<<1, 64, 0, stream>>>(stats3, g_upd, be_upd, sc3, HID);
    k_out<<<1024, 256, 0, stream>>>(u_out, sc3, W_out, b_out, o_out);
}